// Round 2
// baseline (2054.220 us; speedup 1.0000x reference)
//
#include <hip/hip_runtime.h>
#include <hip/hip_bf16.h>

// GraphUpsampler: N=4096 -> M=8192 dense GCN, 3 iterations, out = sigmoid(Xu@Xu.T) f32 [8192,8192].
// R2: barrier-free streaming aggregation (A,B direct-to-VGPR, software pipelined);
//     initial block-adjacency never materialized (A_bf + S0 + 3 small GEMMs).

#define N_NODES 4096
#define M_NODES 8192
#define DIM 128
#define SLICE_ELEMS ((size_t)M_NODES * DIM)

typedef __attribute__((ext_vector_type(4))) float f32x4;
typedef __attribute__((ext_vector_type(8))) short bf16x8;

__device__ __forceinline__ unsigned short f2bf(float f) {
  union { float f; unsigned u; } v; v.f = f;
  unsigned r = v.u + 0x7fffu + ((v.u >> 16) & 1u);   // round-to-nearest-even
  return (unsigned short)(r >> 16);
}
__device__ __forceinline__ float bf2f(unsigned short b) {
  union { unsigned u; float f; } v; v.u = ((unsigned)b) << 16;
  return v.f;
}

__device__ __forceinline__ void gld16(unsigned short* lds, const unsigned short* g) {
  __builtin_amdgcn_global_load_lds(
      (const __attribute__((address_space(1))) unsigned int*)g,
      (__attribute__((address_space(3))) unsigned int*)lds, 16, 0, 0);
}

__device__ __forceinline__ float sigmoidf_(float x) { return 1.0f / (1.0f + __expf(-x)); }

// ---------------- small cast / init kernels ----------------

__global__ void cast_x_kernel(const float* __restrict__ X, unsigned short* __restrict__ Xu,
                              unsigned short* __restrict__ XT) {
  int idx = blockIdx.x * 256 + threadIdx.x;          // over N*DIM
  int i = idx >> 7, c = idx & 127;
  unsigned short b = f2bf(X[idx]);
  Xu[idx] = b;
  XT[(size_t)c * N_NODES + i] = b;                   // X^T [128][4096]
}

__global__ void cast_wup_kernel(const float4* __restrict__ W, ushort4* __restrict__ Wb) {
  int idx = blockIdx.x * 256 + threadIdx.x;          // over N*N/4
  float4 v = W[idx];
  ushort4 o;
  o.x = f2bf(v.x); o.y = f2bf(v.y); o.z = f2bf(v.z); o.w = f2bf(v.w);
  Wb[idx] = o;
}

__global__ void cast_wt_kernel(const float* __restrict__ W, unsigned short* __restrict__ WT) {
  int idx = blockIdx.x * 256 + threadIdx.x;          // 128*128
  int k = idx >> 7, c = idx & 127;
  WT[c * DIM + k] = f2bf(W[idx]);                    // W^T [out c][in k]
}

// A f32 -> bf16 (once) + colsum(A)
__global__ void cast_a_kernel(const float* __restrict__ A, unsigned short* __restrict__ Ab,
                              float* __restrict__ colsumA) {
  int c = blockIdx.x * 256 + threadIdx.x;
  int r0 = blockIdx.y * 128;
  float s = 0.f;
  for (int r = 0; r < 128; ++r) {
    float a = A[(size_t)(r0 + r) * N_NODES + c];
    Ab[(size_t)(r0 + r) * N_NODES + c] = f2bf(a);
    s += a;
  }
  atomicAdd(&colsumA[c], s);
}

__global__ void init_deg_kernel(const float* __restrict__ colsumA, float* __restrict__ deg) {
  int i = blockIdx.x * 256 + threadIdx.x;            // 8192
  deg[i] = (i < N_NODES) ? 2.0f * colsumA[i] : colsumA[i - N_NODES];
}

__global__ void dinv_kernel(const float* __restrict__ deg, float* __restrict__ dinv) {
  int i = blockIdx.x * 256 + threadIdx.x;
  float d = deg[i];
  dinv[i] = d > 0.f ? rsqrtf(d) : 0.f;
}

// ZsumT[c][j] = ZT[c][j] + ZT[c][4096+j]
__global__ void zsum_kernel(const unsigned short* __restrict__ ZT,
                            unsigned short* __restrict__ ZsumT) {
  int idx = blockIdx.x * 256 + threadIdx.x;          // 128*4096
  int c = idx >> 12, j = idx & 4095;
  float v = bf2f(ZT[(size_t)c * M_NODES + j]) + bf2f(ZT[(size_t)c * M_NODES + N_NODES + j]);
  ZsumT[idx] = f2bf(v);
}

// ---------------- barrier-free streaming split-K GEMM ----------------
// C_slice = A[128-rows m0..][kbase..kbase+32*kIters] @ B  (B given transposed: BT[128 n][ldb k])
// A-frags and B-frags load direct global->VGPR; no LDS, no __syncthreads.

__global__ __launch_bounds__(256)
void agg_kernel(const unsigned short* __restrict__ A, long lda,
                const unsigned short* __restrict__ BT, long ldb,
                float* __restrict__ accBase, int sliceOff, long rowOff, int kIters) {
  const int t = threadIdx.x, w = t >> 6, lane = t & 63;
  const int q = lane >> 4, l15 = lane & 15;
  const long m0 = (long)blockIdx.x * 128;
  const long kbase = (long)blockIdx.y * 32L * kIters;

  f32x4 acc[2][8];
#pragma unroll
  for (int a = 0; a < 2; ++a)
#pragma unroll
    for (int b = 0; b < 8; ++b) acc[a][b] = (f32x4)0.f;

  const size_t ar0 = (size_t)(m0 + w * 32 + l15) * lda + kbase + q * 8;
  const size_t ar1 = ar0 + (size_t)16 * lda;
  const size_t bbase = kbase + q * 8;

  bf16x8 a0[2], a1[2], bf[2][8];

#define LOADG(KT, S)                                                              \
  do {                                                                            \
    const size_t kk_ = (size_t)(KT) * 32;                                         \
    a0[S] = *(const bf16x8*)&A[ar0 + kk_];                                        \
    a1[S] = *(const bf16x8*)&A[ar1 + kk_];                                        \
    _Pragma("unroll")                                                             \
    for (int nt = 0; nt < 8; ++nt)                                                \
      bf[S][nt] = *(const bf16x8*)&BT[(size_t)(nt * 16 + l15) * ldb + bbase + kk_];\
  } while (0)

  LOADG(0, 0);
#pragma unroll 2
  for (int kt = 0; kt < kIters; ++kt) {
    const int cur = kt & 1, nxt = cur ^ 1;
    if (kt + 1 < kIters) LOADG(kt + 1, nxt);
#pragma unroll
    for (int nt = 0; nt < 8; ++nt) {
      acc[0][nt] = __builtin_amdgcn_mfma_f32_16x16x32_bf16(a0[cur], bf[cur][nt], acc[0][nt], 0, 0, 0);
      acc[1][nt] = __builtin_amdgcn_mfma_f32_16x16x32_bf16(a1[cur], bf[cur][nt], acc[1][nt], 0, 0, 0);
    }
  }
#undef LOADG

  float* C = accBase + (size_t)(sliceOff + blockIdx.y) * SLICE_ELEMS + (size_t)(rowOff + m0) * DIM;
#pragma unroll
  for (int mt = 0; mt < 2; ++mt)
#pragma unroll
    for (int nt = 0; nt < 8; ++nt)
#pragma unroll
      for (int i = 0; i < 4; ++i)
        C[(size_t)(w * 32 + mt * 16 + q * 4 + i) * DIM + nt * 16 + l15] = acc[mt][nt][i];
}

// sum split partials + epilogue -> bf16
// mode 0: v = s + bias_row[row]
// mode 1: v = relu(dinv[row]*s + bias_col[c])
// rows < rowSplit sum nLo slices, else nHi slices.
__global__ void reduce_acc_kernel(const float* __restrict__ acc,
                                  unsigned short* __restrict__ dst,
                                  const float* __restrict__ bias_row,
                                  const float* __restrict__ bias_col,
                                  const float* __restrict__ dinv, int mode,
                                  int nLo, int nHi, int rowSplit) {
  int idx = blockIdx.x * 256 + threadIdx.x;
  int row = idx >> 7, c = idx & 127;
  int ns = (row < rowSplit) ? nLo : nHi;
  float s = 0.f;
  for (int sp = 0; sp < ns; ++sp) s += acc[(size_t)sp * SLICE_ELEMS + idx];
  float v;
  if (mode == 0) v = s + bias_row[row];
  else { v = dinv[row] * s + bias_col[c]; v = fmaxf(v, 0.f); }
  dst[idx] = f2bf(v);
}

// ---------------- rebuild: out = sigmoid(XA @ XB^T), K=128 ----------------
// MODE 0: bf16 out + fused column sums into deg.  MODE 1: f32 out (final).

template <int MODE>
__global__ __launch_bounds__(256)
void rebuild_kernel(const unsigned short* __restrict__ XA,
                    const unsigned short* __restrict__ XB,
                    void* __restrict__ out, long ldo, float* __restrict__ deg) {
  __shared__ __align__(16) unsigned short smem[32768];   // lA[4][128][32] + lB[4][128][32]
  __shared__ float lcol[128];
  unsigned short* lA = smem;
  unsigned short* lB = smem + 16384;
  const int t = threadIdx.x, w = t >> 6, lane = t & 63;
  const int q = lane >> 4, l15 = lane & 15;
  const int i0 = blockIdx.x * 128, j0 = blockIdx.y * 128;
  const int srow = t >> 2, schk = t & 3;
#pragma unroll
  for (int kk = 0; kk < 4; ++kk)
#pragma unroll
    for (int h = 0; h < 2; ++h) {
      gld16(&lA[kk * 4096 + h * 2048 + t * 8],
            &XA[(size_t)(i0 + h * 64 + srow) * DIM + kk * 32 + schk * 8]);
      gld16(&lB[kk * 4096 + h * 2048 + t * 8],
            &XB[(size_t)(j0 + h * 64 + srow) * DIM + kk * 32 + schk * 8]);
    }
  if (MODE == 0 && t < 128) lcol[t] = 0.f;
  __syncthreads();

  f32x4 acc[2][8];
#pragma unroll
  for (int a = 0; a < 2; ++a)
#pragma unroll
    for (int b = 0; b < 8; ++b) acc[a][b] = (f32x4)0.f;

#pragma unroll
  for (int kk = 0; kk < 4; ++kk) {
    bf16x8 a0 = *(const bf16x8*)&lA[kk * 4096 + (w * 32 + l15) * 32 + q * 8];
    bf16x8 a1 = *(const bf16x8*)&lA[kk * 4096 + (w * 32 + 16 + l15) * 32 + q * 8];
#pragma unroll
    for (int nt = 0; nt < 8; ++nt) {
      bf16x8 b = *(const bf16x8*)&lB[kk * 4096 + (nt * 16 + l15) * 32 + q * 8];
      acc[0][nt] = __builtin_amdgcn_mfma_f32_16x16x32_bf16(a0, b, acc[0][nt], 0, 0, 0);
      acc[1][nt] = __builtin_amdgcn_mfma_f32_16x16x32_bf16(a1, b, acc[1][nt], 0, 0, 0);
    }
  }
  __syncthreads();   // staging reads done; smem reusable as C-tile

  if (MODE == 0) {
    unsigned short* lC = smem;   // [128][136] bf16
#pragma unroll
    for (int mt = 0; mt < 2; ++mt)
#pragma unroll
      for (int nt = 0; nt < 8; ++nt) {
        float cs = 0.f;
#pragma unroll
        for (int i = 0; i < 4; ++i) {
          float sv = sigmoidf_(acc[mt][nt][i]);
          cs += sv;
          lC[(w * 32 + mt * 16 + q * 4 + i) * 136 + nt * 16 + l15] = f2bf(sv);
        }
        cs += __shfl_xor(cs, 16);
        cs += __shfl_xor(cs, 32);
        if (lane < 16) atomicAdd(&lcol[nt * 16 + lane], cs);
      }
    __syncthreads();
    unsigned short* og = (unsigned short*)out;
#pragma unroll
    for (int cc = 0; cc < 8; ++cc) {
      int ch = t + cc * 256;                     // 0..2047
      int row = ch >> 4, c16 = ch & 15;
      *(bf16x8*)&og[(size_t)(i0 + row) * ldo + j0 + c16 * 8] =
          *(const bf16x8*)&lC[row * 136 + c16 * 8];
    }
    if (t < 128) atomicAdd(&deg[j0 + t], lcol[t]);
  } else {
    float* og = (float*)out;
#pragma unroll
    for (int mt = 0; mt < 2; ++mt)
#pragma unroll
      for (int nt = 0; nt < 8; ++nt)
#pragma unroll
        for (int i = 0; i < 4; ++i)
          og[(size_t)(i0 + w * 32 + mt * 16 + q * 4 + i) * ldo + j0 + nt * 16 + l15] =
              sigmoidf_(acc[mt][nt][i]);
  }
}

// ---------------- Z^T = (dinv ⊙ (Xu @ W)) transposed, [128][8192] ----------------

__global__ __launch_bounds__(256)
void yz_kernel(const unsigned short* __restrict__ Xu, const unsigned short* __restrict__ WT,
               const float* __restrict__ dinv, unsigned short* __restrict__ ZT, int ldz) {
  __shared__ __align__(16) unsigned short smem[32768];
  unsigned short* lA = smem;
  unsigned short* lB = smem + 16384;
  const int t = threadIdx.x, w = t >> 6, lane = t & 63;
  const int q = lane >> 4, l15 = lane & 15;
  const int r0 = blockIdx.x * 128;
  const int srow = t >> 2, schk = t & 3;
#pragma unroll
  for (int kk = 0; kk < 4; ++kk)
#pragma unroll
    for (int h = 0; h < 2; ++h) {
      gld16(&lA[kk * 4096 + h * 2048 + t * 8],
            &Xu[(size_t)(r0 + h * 64 + srow) * DIM + kk * 32 + schk * 8]);
      gld16(&lB[kk * 4096 + h * 2048 + t * 8],
            &WT[(size_t)(h * 64 + srow) * DIM + kk * 32 + schk * 8]);
    }
  __syncthreads();

  f32x4 acc[2][8];
#pragma unroll
  for (int a = 0; a < 2; ++a)
#pragma unroll
    for (int b = 0; b < 8; ++b) acc[a][b] = (f32x4)0.f;

#pragma unroll
  for (int kk = 0; kk < 4; ++kk) {
    bf16x8 a0 = *(const bf16x8*)&lA[kk * 4096 + (w * 32 + l15) * 32 + q * 8];
    bf16x8 a1 = *(const bf16x8*)&lA[kk * 4096 + (w * 32 + 16 + l15) * 32 + q * 8];
#pragma unroll
    for (int nt = 0; nt < 8; ++nt) {
      bf16x8 b = *(const bf16x8*)&lB[kk * 4096 + (nt * 16 + l15) * 32 + q * 8];
      acc[0][nt] = __builtin_amdgcn_mfma_f32_16x16x32_bf16(a0, b, acc[0][nt], 0, 0, 0);
      acc[1][nt] = __builtin_amdgcn_mfma_f32_16x16x32_bf16(a1, b, acc[1][nt], 0, 0, 0);
    }
  }
  __syncthreads();
  unsigned short* lT = smem;   // transposed tile [c 128][r 136]
#pragma unroll
  for (int mt = 0; mt < 2; ++mt)
#pragma unroll
    for (int nt = 0; nt < 8; ++nt)
#pragma unroll
      for (int i = 0; i < 4; ++i) {
        int r = w * 32 + mt * 16 + q * 4 + i;
        lT[(nt * 16 + l15) * 136 + r] = f2bf(dinv[r0 + r] * acc[mt][nt][i]);
      }
  __syncthreads();
#pragma unroll
  for (int cc = 0; cc < 8; ++cc) {
    int ch = t + cc * 256;
    int c = ch >> 4, c16 = ch & 15;
    *(bf16x8*)&ZT[(size_t)c * ldz + r0 + c16 * 8] = *(const bf16x8*)&lT[c * 136 + c16 * 8];
  }
}

// ---------------- driver ----------------

extern "C" void kernel_launch(void* const* d_in, const int* in_sizes, int n_in,
                              void* d_out, int out_size, void* d_ws, size_t ws_size,
                              hipStream_t stream) {
  (void)in_sizes; (void)n_in; (void)out_size;
  const float* X   = (const float*)d_in[0];
  const float* A   = (const float*)d_in[1];
  const float* Wup = (const float*)d_in[2];
  const float* bup = (const float*)d_in[3];
  const float* W1  = (const float*)d_in[4];
  const float* b1  = (const float*)d_in[5];
  const float* W2  = (const float*)d_in[6];
  const float* b2  = (const float*)d_in[7];

  const size_t ADJ_BYTES = (size_t)M_NODES * M_NODES * 2;
  char* ws = (char*)d_ws;
  size_t off = 0;
  auto alloc = [&](size_t bytes) {
    char* p = ws + off;
    off += (bytes + 255) & ~(size_t)255;
    return p;
  };
  float*          accb    = (float*)alloc(16 * SLICE_ELEMS * 4);                 // 67 MB
  unsigned short* Xu      = (unsigned short*)alloc((size_t)M_NODES * DIM * 2);
  unsigned short* ZT      = (unsigned short*)alloc((size_t)DIM * M_NODES * 2);
  unsigned short* XT      = (unsigned short*)alloc((size_t)DIM * N_NODES * 2);
  unsigned short* ZsumT   = (unsigned short*)alloc((size_t)DIM * N_NODES * 2);
  unsigned short* W1T     = (unsigned short*)alloc(DIM * DIM * 2);
  unsigned short* W2T     = (unsigned short*)alloc(DIM * DIM * 2);
  float*          colsumA = (float*)alloc(N_NODES * 4);
  float*          deg     = (float*)alloc(M_NODES * 4);
  float*          dinv    = (float*)alloc(M_NODES * 4);
  unsigned short* Abf     = (unsigned short*)alloc((size_t)N_NODES * N_NODES * 2);  // 33.5 MB
  unsigned short* S0      = (unsigned short*)alloc((size_t)N_NODES * N_NODES * 2);  // 33.5 MB

  unsigned short* Adj;
  if (ws_size >= off + ADJ_BYTES) Adj = (unsigned short*)(ws + off);
  else                            Adj = (unsigned short*)d_out;  // Adj dead before final write
  unsigned short* Wupb = Adj;   // W_up bf16 aliases Adj (consumed before Adj first written)

  unsigned short* XuNew = Xu + (size_t)N_NODES * DIM;

  hipMemsetAsync(colsumA, 0, N_NODES * 4, stream);
  cast_x_kernel<<<N_NODES * DIM / 256, 256, 0, stream>>>(X, Xu, XT);
  cast_wup_kernel<<<((size_t)N_NODES * N_NODES / 4) / 256, 256, 0, stream>>>(
      (const float4*)Wup, (ushort4*)Wupb);
  cast_wt_kernel<<<64, 256, 0, stream>>>(W1, W1T);
  cast_wt_kernel<<<64, 256, 0, stream>>>(W2, W2T);

  // new = W_up @ X (+ b_up per-row): K=4096, 8 splits x 512
  agg_kernel<<<dim3(N_NODES / 128, 8), 256, 0, stream>>>(
      Wupb, N_NODES, XT, N_NODES, accb, 0, 0, 16);
  reduce_acc_kernel<<<N_NODES * DIM / 256, 256, 0, stream>>>(
      accb, XuNew, bup, nullptr, nullptr, 0, 8, 8, N_NODES);

  // A -> bf16 + colsum; deg; S0 = sigmoid(new@new^T) + colsum fused
  cast_a_kernel<<<dim3(N_NODES / 256, N_NODES / 128), 256, 0, stream>>>(A, Abf, colsumA);
  init_deg_kernel<<<M_NODES / 256, 256, 0, stream>>>(colsumA, deg);
  rebuild_kernel<0><<<dim3(N_NODES / 128, N_NODES / 128), 256, 0, stream>>>(
      XuNew, XuNew, S0, N_NODES, deg + N_NODES);
  dinv_kernel<<<M_NODES / 256, 256, 0, stream>>>(deg, dinv);

  // ---- iter 0, conv1 via block structure ----
  yz_kernel<<<M_NODES / 128, 256, 0, stream>>>(Xu, W1T, dinv, ZT, M_NODES);
  zsum_kernel<<<DIM * N_NODES / 256, 256, 0, stream>>>(ZT, ZsumT);
  // C_top = A @ (Zt+Zb)        -> slices 0..7, rows 0..4095
  agg_kernel<<<dim3(N_NODES / 128, 8), 256, 0, stream>>>(
      Abf, N_NODES, ZsumT, N_NODES, accb, 0, 0, 16);
  // C_bot = A @ Zt             -> slices 0..7, rows 4096..8191
  agg_kernel<<<dim3(N_NODES / 128, 8), 256, 0, stream>>>(
      Abf, N_NODES, ZT, M_NODES, accb, 0, N_NODES, 16);
  // C_bot += S0 @ Zb           -> slices 8..15, rows 4096..8191
  agg_kernel<<<dim3(N_NODES / 128, 8), 256, 0, stream>>>(
      S0, N_NODES, ZT + N_NODES, M_NODES, accb, 8, N_NODES, 16);
  reduce_acc_kernel<<<M_NODES * DIM / 256, 256, 0, stream>>>(
      accb, Xu, nullptr, b1, dinv, 1, 8, 16, N_NODES);

  for (int it = 0; it < 3; ++it) {
    if (it > 0) {
      // conv1 on full Adj (carried from previous iteration's mid-loop rebuild)
      yz_kernel<<<M_NODES / 128, 256, 0, stream>>>(Xu, W1T, dinv, ZT, M_NODES);
      agg_kernel<<<dim3(M_NODES / 128, 8), 256, 0, stream>>>(
          Adj, M_NODES, ZT, M_NODES, accb, 0, 0, 32);
      reduce_acc_kernel<<<M_NODES * DIM / 256, 256, 0, stream>>>(
          accb, Xu, nullptr, b1, dinv, 1, 8, 8, 0);
    }
    // mid-loop Adj rebuild + deg
    hipMemsetAsync(deg, 0, M_NODES * 4, stream);
    rebuild_kernel<0><<<dim3(M_NODES / 128, M_NODES / 128), 256, 0, stream>>>(
        Xu, Xu, Adj, M_NODES, deg);
    dinv_kernel<<<M_NODES / 256, 256, 0, stream>>>(deg, dinv);
    // conv2
    yz_kernel<<<M_NODES / 128, 256, 0, stream>>>(Xu, W2T, dinv, ZT, M_NODES);
    agg_kernel<<<dim3(M_NODES / 128, 8), 256, 0, stream>>>(
        Adj, M_NODES, ZT, M_NODES, accb, 0, 0, 32);
    reduce_acc_kernel<<<M_NODES * DIM / 256, 256, 0, stream>>>(
        accb, Xu, nullptr, b2, dinv, 1, 8, 8, 0);
    if (it == 2)
      rebuild_kernel<1><<<dim3(M_NODES / 128, M_NODES / 128), 256, 0, stream>>>(
          Xu, Xu, d_out, M_NODES, nullptr);
  }
}